// Round 10
// baseline (338.621 us; speedup 1.0000x reference)
//
#include <hip/hip_runtime.h>
#include <hip/hip_bf16.h>
#include <stdint.h>

typedef __bf16 bf16;
typedef __attribute__((ext_vector_type(8))) __bf16 bf16x8;
typedef __attribute__((ext_vector_type(4))) float f32x4;

#define NH     16
#define DM     1024
#define HS     64
#define BATCH  4
#define SEQ    2048
#define N_XE   (BATCH * SEQ * DM)   // 8388608
#define N_WOE  (DM * DM)            // 1048576

// async global->LDS, 16B per lane; LDS dest is wave-uniform base + lane*16
__device__ __forceinline__ void async16(void* lds, const void* g) {
  __builtin_amdgcn_global_load_lds(
      (const uint32_t __attribute__((address_space(1)))*)g,
      (uint32_t __attribute__((address_space(3)))*)lds,
      16, 0, 0);
}

__device__ __forceinline__ f32x4 mfma16(bf16x8 a, bf16x8 b, f32x4 c) {
  return __builtin_amdgcn_mfma_f32_16x16x32_bf16(a, b, c, 0, 0, 0);
}

// ---- dtype probe: bf16 data -> even u16s are sane bf16; f32 data -> low
// halves of floats have uniform-random exponent fields. flag=1 means f32.
__global__ void detect_mode(const unsigned short* __restrict__ x, int* flag) {
  int lane = threadIdx.x & 63;
  unsigned short v = x[2 * lane];
  int e = (v >> 7) & 0xFF;
  int sane = (e >= 90 && e <= 160) ? 1 : 0;
  #pragma unroll
  for (int s = 1; s < 64; s <<= 1) sane += __shfl_xor(sane, s, 64);
  if (threadIdx.x == 0) *flag = (sane >= 48) ? 0 : 1;
}

// ---- convert x and Wo to bf16 (or copy if already bf16) -----------------
__global__ __launch_bounds__(256)
void convert_in(const void* __restrict__ x, const void* __restrict__ Wo,
                bf16* __restrict__ xb, bf16* __restrict__ Wob,
                const int* __restrict__ flagp) {
  const int f32m = *flagp;
  size_t base = ((size_t)blockIdx.x * 256 + threadIdx.x) * 8;
  const void* src; bf16* dst; size_t off;
  if (base < (size_t)N_XE) { src = x;  dst = xb;  off = base; }
  else                     { src = Wo; dst = Wob; off = base - N_XE; }
  if (f32m) {
    const float* s = (const float*)src + off;
    float4 a = *(const float4*)s;
    float4 b = *(const float4*)(s + 4);
    bf16x8 o;
    o[0] = (bf16)a.x; o[1] = (bf16)a.y; o[2] = (bf16)a.z; o[3] = (bf16)a.w;
    o[4] = (bf16)b.x; o[5] = (bf16)b.y; o[6] = (bf16)b.z; o[7] = (bf16)b.w;
    *(bf16x8*)(dst + off) = o;
  } else {
    *(bf16x8*)(dst + off) = *(const bf16x8*)((const bf16*)src + off);
  }
}

// ------------- weight transpose: WT[z][n=h*64+s][d] = W_z[h][d][s] --------
__global__ __launch_bounds__(256)
void transpose_w(const void* __restrict__ Wq, const void* __restrict__ Wk,
                 const void* __restrict__ Wv, bf16* __restrict__ WT,
                 const int* __restrict__ flagp) {
  __shared__ bf16 Ts[64][72];
  const int f32m = *flagp;
  const void* W = (blockIdx.y == 0) ? Wq : (blockIdx.y == 1) ? Wk : Wv;
  bf16* dst = WT + (size_t)blockIdx.y * DM * DM;
  const int h  = blockIdx.x >> 4;
  const int d0 = (blockIdx.x & 15) * 64;
  const int tid = threadIdx.x;
  #pragma unroll
  for (int p = 0; p < 2; ++p) {
    int idx = p * 256 + tid;
    int dr = idx >> 3, c = idx & 7;
    size_t eoff = (size_t)(h * DM + d0 + dr) * HS + c * 8;
    bf16x8 v;
    if (f32m) {
      const float* s = (const float*)W + eoff;
      #pragma unroll
      for (int j = 0; j < 8; ++j) v[j] = (bf16)s[j];
    } else {
      v = *(const bf16x8*)((const bf16*)W + eoff);
    }
    #pragma unroll
    for (int j = 0; j < 8; ++j) Ts[c * 8 + j][dr] = v[j];
  }
  __syncthreads();
  #pragma unroll
  for (int p = 0; p < 2; ++p) {
    int idx = p * 256 + tid;
    int sr = idx >> 3, c = idx & 7;
    bf16x8 v = *(const bf16x8*)(&Ts[sr][c * 8]);
    *(bf16x8*)(dst + (size_t)(h * 64 + sr) * DM + d0 + c * 8) = v;
  }
}

// ====== 256x256 bt-GEMM core: 8 waves (2Mx4N), per-wave 128x64 ============
// LDS-BW analysis (per K-step-32 per CU, 1 block):
//   MFMA 4.2 MFLOP/3375 = 1244 cy;  LDS reads A*4amp+B*2amp=96KB + DMA
//   writes 32KB = 1024 cy  -> MFMA-bound (ratio 0.82), vs 1.23+conflicts
//   for the old 128^2/64x64 shape. Swizzle (chunk ^= (row>>1)&3, both
//   sides) kills the 8-way row-alias conflict of [row][32] tiles.
// Ring-3 LDS (96 KiB), stage depth 2, counted vmcnt(8) - never drains.
#define GKT 32
template<typename EpiF>
__device__ __forceinline__ void gemm256_bt(const bf16* __restrict__ A,
                                           const bf16* __restrict__ BT,
                                           int m0, int n0, EpiF epi) {
  __shared__ bf16 As[3][256 * 32];
  __shared__ bf16 Bs[3][256 * 32];
  const int tid  = threadIdx.x;
  const int wid  = tid >> 6, lane = tid & 63;
  const int wr = wid >> 2, wc = wid & 3;       // 2M x 4N wave grid
  const int fr = lane & 15, fg = lane >> 4;
  const int srow = lane >> 2;                  // 16 rows per 1KB issue
  const int schk = (lane & 3) ^ ((lane >> 3) & 3);  // pre-swizzled src chunk
  f32x4 acc[8][4] = {};

  auto STAGE = [&](int kt, int buf) {
    #pragma unroll
    for (int i = 0; i < 2; ++i) {
      int row = wid * 32 + i * 16 + srow;      // wave-uniform base rows
      async16((char*)&As[buf][0] + wid * 2048 + i * 1024,
              A + (size_t)(m0 + row) * DM + kt * 32 + schk * 8);
      async16((char*)&Bs[buf][0] + wid * 2048 + i * 1024,
              BT + (size_t)(n0 + row) * DM + kt * 32 + schk * 8);
    }
  };

  STAGE(0, 0); STAGE(1, 1);
  int cbuf = 0, sbuf = 2;
  #pragma unroll 1
  for (int kt = 0; kt < GKT; ++kt) {
    if (kt + 2 < GKT) {
      STAGE(kt + 2, sbuf);
      sbuf = (sbuf == 2) ? 0 : sbuf + 1;
      asm volatile("s_waitcnt vmcnt(8)" ::: "memory");   // tile kt landed
    } else if (kt + 1 < GKT) {
      asm volatile("s_waitcnt vmcnt(4)" ::: "memory");
    } else {
      asm volatile("s_waitcnt vmcnt(0)" ::: "memory");
    }
    __builtin_amdgcn_s_barrier();      // tile kt visible to all waves
    const bf16* Ab = &As[cbuf][0];
    const bf16* Bb = &Bs[cbuf][0];
    bf16x8 af[8], bv[4];
    #pragma unroll
    for (int i = 0; i < 8; ++i) {
      int r = wr * 128 + i * 16 + fr;
      af[i] = *(const bf16x8*)(Ab + r * 32 + ((fg ^ ((r >> 1) & 3)) * 8));
    }
    #pragma unroll
    for (int i = 0; i < 4; ++i) {
      int r = wc * 64 + i * 16 + fr;
      bv[i] = *(const bf16x8*)(Bb + r * 32 + ((fg ^ ((r >> 1) & 3)) * 8));
    }
    __builtin_amdgcn_s_setprio(1);
    #pragma unroll
    for (int mi = 0; mi < 8; ++mi)
      #pragma unroll
      for (int ni = 0; ni < 4; ++ni)
        acc[mi][ni] = mfma16(af[mi], bv[ni], acc[mi][ni]);
    __builtin_amdgcn_s_setprio(0);
    __builtin_amdgcn_s_barrier();      // reads of cbuf done before re-stage
    cbuf = (cbuf == 2) ? 0 : cbuf + 1;
  }
  #pragma unroll
  for (int mi = 0; mi < 8; ++mi)
    #pragma unroll
    for (int ni = 0; ni < 4; ++ni)
      #pragma unroll
      for (int rr = 0; rr < 4; ++rr) {
        int m = m0 + wr * 128 + mi * 16 + fg * 4 + rr;
        int n = wc * 64 + ni * 16 + fr;          // relative to n0
        epi(m, n, acc[mi][ni][rr]);
      }
}

// QKV projection: grid(384) = 32 m-tiles x (3z x 4 n-tiles), XCD-chunked:
// xcd = bid&7 owns m-tiles 4*xcd..+3 (x-panel L2 locality).
__global__ __launch_bounds__(512, 2)
void qkv_gemm(const bf16* __restrict__ x, const bf16* __restrict__ WT,
              bf16* __restrict__ Qb, bf16* __restrict__ Kb, bf16* __restrict__ Vt) {
  const int xcd = blockIdx.x & 7;
  const int k   = blockIdx.x >> 3;
  const int m_tile = xcd * 4 + k / 12;
  const int nz = k % 12;
  const int z  = nz >> 2;
  const int nb = (nz & 3) * 256;
  const int m0 = m_tile * 256;
  const bf16* BT = WT + (size_t)z * DM * DM + (size_t)nb * DM;
  gemm256_bt(x, BT, m0, 0, [&](int m, int nrel, float v) {
    int n = nb + nrel;
    int b = m >> 11, t = m & 2047, h = n >> 6, s = n & 63;
    if (z == 0)
      Qb[((size_t)(b * NH + h) * SEQ + t) * HS + s] = (bf16)v;
    else if (z == 1)
      Kb[((size_t)(b * NH + h) * SEQ + t) * HS + s] = (bf16)v;
    else
      Vt[((size_t)(b * NH + h) * HS + s) * SEQ + t] = (bf16)v;
  });
}

// Output projection: grid(128) = 32 m-tiles x 4 n-tiles, XCD-chunked.
__global__ __launch_bounds__(512, 2)
void out_gemm(const bf16* __restrict__ att, const bf16* __restrict__ Wob,
              const void* __restrict__ bo, void* __restrict__ out,
              const int* __restrict__ flagp) {
  const int f32m = *flagp;
  const int xcd = blockIdx.x & 7;
  const int k   = blockIdx.x >> 3;
  const int m_tile = xcd * 4 + (k >> 2);
  const int nb = (k & 3) * 256;
  const int m0 = m_tile * 256;
  const bf16* BT = Wob + (size_t)nb * DM;
  gemm256_bt(att, BT, m0, 0, [&](int m, int nrel, float v) {
    int n = nb + nrel;
    float bv = f32m ? ((const float*)bo)[n] : (float)((const bf16*)bo)[n];
    float o = v + bv;
    if (f32m) ((float*)out)[(size_t)m * DM + n] = o;
    else      ((bf16*)out)[(size_t)m * DM + n] = (bf16)o;
  });
}

// -------------------- causal flash attention v4 (unchanged) ---------------
#define KVB  64
__global__ __launch_bounds__(256, 2)
void attn_kernel(const bf16* __restrict__ Qb, const bf16* __restrict__ Kb,
                 const bf16* __restrict__ Vt, bf16* __restrict__ att) {
  __shared__ bf16 Ks[2][64][64];      // [buf][kv][d]  (chunks swizzled)
  __shared__ bf16 Vs[2][64][64];      // [buf][d][kv]  (chunks swizzled)
  __shared__ bf16 Ps[4][2][16][64];   // per-wave P    (chunks swizzled)
  const int wave = threadIdx.x >> 6, lane = threadIdx.x & 63;
  const int fr = lane & 15, fg = lane >> 4;
  const int pair = blockIdx.x;        // 0..7
  const int bh = blockIdx.y;
  const bf16* Qp = Qb + (size_t)bh * SEQ * HS;
  const bf16* Kp = Kb + (size_t)bh * SEQ * HS;
  const bf16* Vp = Vt + (size_t)bh * HS * SEQ;
  const int b = bh >> 4, h = bh & 15;

  const int srow8 = lane >> 3;
  const int schk  = (lane & 7) ^ srow8;

  #pragma unroll
  for (int seg = 0; seg < 2; ++seg) {
    const int qb = seg == 0 ? (15 - pair) : pair;   // heavy member first
    const int q0 = qb * 128 + wave * 32;
    const int kv_hi = q0 + 32;
    const int nt = (qb + 1) * 2;

    bf16x8 qf[2][2];
    #pragma unroll
    for (int qt = 0; qt < 2; ++qt)
      #pragma unroll
      for (int hh = 0; hh < 2; ++hh)
        qf[qt][hh] = *(const bf16x8*)(Qp + (size_t)(q0 + qt * 16 + fr) * HS + hh * 32 + fg * 8);

    float rs[2][4] = {};
    f32x4 accO[2][4] = {};

    auto STAGE = [&](int buf, int kvb) {
      #pragma unroll
      for (int i = 0; i < 2; ++i) {
        int r8 = wave * 16 + i * 8;
        async16(&Ks[buf][r8][0], Kp + (size_t)(kvb + r8 + srow8) * HS + schk * 8);
        async16(&Vs[buf][r8][0], Vp + (size_t)(r8 + srow8) * SEQ + kvb + schk * 8);
      }
    };

    STAGE(0, 0);
    for (int t = 0; t < nt; ++t) {
      const int buf = t & 1;
      const int kvb = t * KVB;
      if (t + 1 < nt) {
        STAGE(buf ^ 1, kvb + KVB);
        asm volatile("s_waitcnt vmcnt(4)" ::: "memory");  // tile t landed
      } else {
        asm volatile("s_waitcnt vmcnt(0)" ::: "memory");
      }
      __builtin_amdgcn_s_barrier();      // all waves' tile-t data visible
      if (kvb < kv_hi) {
        bf16x8 kf[4][2];
        #pragma unroll
        for (int s = 0; s < 4; ++s)
          #pragma unroll
          for (int hh = 0; hh < 2; ++hh)
            kf[s][hh] = *(const bf16x8*)(&Ks[buf][s * 16 + fr][((hh * 4 + fg) ^ (fr & 7)) * 8]);
        // WAR: previous tile's P reads retired before overwriting Ps
        asm volatile("s_waitcnt lgkmcnt(0)" ::: "memory");

        #pragma unroll
        for (int qt = 0; qt < 2; ++qt) {
          f32x4 sc[4];
          #pragma unroll
          for (int s = 0; s < 4; ++s) {
            sc[s] = f32x4{0.f, 0.f, 0.f, 0.f};
            sc[s] = mfma16(qf[qt][0], kf[s][0], sc[s]);
            sc[s] = mfma16(qf[qt][1], kf[s][1], sc[s]);
          }
          #pragma unroll
          for (int s = 0; s < 4; ++s)
            #pragma unroll
            for (int r = 0; r < 4; ++r) {
              int qrow = q0 + qt * 16 + fg * 4 + r;
              int col  = kvb + s * 16 + fr;
              float p = __expf(sc[s][r] * 0.125f);
              p = (col <= qrow) ? p : 0.f;
              rs[qt][r] += p;
              int row = fg * 4 + r;
              int swz = (s * 2 + (fr >> 3)) ^ (row & 7);
              Ps[wave][qt][row][swz * 8 + (fr & 7)] = (bf16)p;
            }
        }
        asm volatile("s_waitcnt lgkmcnt(0)" ::: "memory");  // P visible
        __builtin_amdgcn_sched_barrier(0);
        bf16x8 pf[2][2];
        #pragma unroll
        for (int qt = 0; qt < 2; ++qt)
          #pragma unroll
          for (int kc = 0; kc < 2; ++kc)
            pf[qt][kc] = *(const bf16x8*)(&Ps[wave][qt][fr][(((kc * 4 + fg) ^ (fr & 7))) * 8]);
        #pragma unroll
        for (int st = 0; st < 4; ++st) {
          bf16x8 vf0 = *(const bf16x8*)(&Vs[buf][st * 16 + fr][((fg) ^ (fr & 7)) * 8]);
          bf16x8 vf1 = *(const bf16x8*)(&Vs[buf][st * 16 + fr][((4 + fg) ^ (fr & 7)) * 8]);
          #pragma unroll
          for (int qt = 0; qt < 2; ++qt) {
            accO[qt][st] = mfma16(pf[qt][0], vf0, accO[qt][st]);
            accO[qt][st] = mfma16(pf[qt][1], vf1, accO[qt][st]);
          }
        }
      }
      __builtin_amdgcn_s_barrier();      // all reads of buf done before reuse
    }

    // epilogue: one cross-lane sum reduce (over the 16 fr lanes), then store
    #pragma unroll
    for (int sh = 1; sh < 16; sh <<= 1)
      #pragma unroll
      for (int qt = 0; qt < 2; ++qt)
        #pragma unroll
        for (int r = 0; r < 4; ++r)
          rs[qt][r] += __shfl_xor(rs[qt][r], sh, 64);
    #pragma unroll
    for (int qt = 0; qt < 2; ++qt)
      #pragma unroll
      for (int st = 0; st < 4; ++st)
        #pragma unroll
        for (int r = 0; r < 4; ++r) {
          int qrow = q0 + qt * 16 + fg * 4 + r;
          float o = accO[qt][st][r] / rs[qt][r];
          att[((size_t)(b * SEQ + qrow)) * DM + h * 64 + st * 16 + fr] = (bf16)o;
        }
  }
}

// --------------------------------------------------------------------------
extern "C" void kernel_launch(void* const* d_in, const int* in_sizes, int n_in,
                              void* d_out, int out_size, void* d_ws, size_t ws_size,
                              hipStream_t stream) {
  const void* x  = d_in[0];
  const void* Wq = d_in[1];
  const void* Wk = d_in[2];
  const void* Wv = d_in[3];
  const void* Wo = d_in[4];
  const void* bo = d_in[5];

  char* ws = (char*)d_ws;
  int*  flag = (int*)ws;
  bf16* xb  = (bf16*)(ws + 256);                        // 16 MiB
  bf16* WT  = (bf16*)(ws + 256 + ((size_t)16 << 20));   // 6 MiB (QKV^T)
  bf16* Wob = (bf16*)(ws + 256 + ((size_t)22 << 20));   // 2 MiB
  bf16* Qb  = (bf16*)(ws + 256 + ((size_t)24 << 20));   // 16 MiB
  bf16* Kb  = (bf16*)(ws + 256 + ((size_t)40 << 20));   // 16 MiB
  bf16* Vt  = (bf16*)(ws + 256 + ((size_t)56 << 20));   // 16 MiB -> 72 MiB
  bf16* att = xb;   // x is consumed after qkv_gemm; reuse its buffer

  detect_mode<<<1, 64, 0, stream>>>((const unsigned short*)x, flag);
  convert_in<<<(N_XE + N_WOE) / 2048, 256, 0, stream>>>(x, Wo, xb, Wob, flag);
  transpose_w<<<dim3(256, 3), 256, 0, stream>>>(Wq, Wk, Wv, WT, flag);
  qkv_gemm<<<dim3(384), 512, 0, stream>>>(xb, WT, Qb, Kb, Vt);
  attn_kernel<<<dim3(8, BATCH * NH), 256, 0, stream>>>(Qb, Kb, Vt, att);
  out_gemm<<<dim3(128), 512, 0, stream>>>(att, Wob, bo, d_out, flag);
}

// Round 11
// 276.009 us; speedup vs baseline: 1.2268x; 1.2268x over previous
//
#include <hip/hip_runtime.h>
#include <hip/hip_bf16.h>
#include <stdint.h>

typedef __bf16 bf16;
typedef __attribute__((ext_vector_type(8))) __bf16 bf16x8;
typedef __attribute__((ext_vector_type(4))) float f32x4;

#define NH     16
#define DM     1024
#define HS     64
#define BATCH  4
#define SEQ    2048
#define N_XE   (BATCH * SEQ * DM)   // 8388608
#define N_WOE  (DM * DM)            // 1048576
#define NCONV  ((N_XE + N_WOE) / 2048)   // 4608 convert blocks

// async global->LDS, 16B per lane; LDS dest is wave-uniform base + lane*16
__device__ __forceinline__ void async16(void* lds, const void* g) {
  __builtin_amdgcn_global_load_lds(
      (const uint32_t __attribute__((address_space(1)))*)g,
      (uint32_t __attribute__((address_space(3)))*)lds,
      16, 0, 0);
}

__device__ __forceinline__ f32x4 mfma16(bf16x8 a, bf16x8 b, f32x4 c) {
  return __builtin_amdgcn_mfma_f32_16x16x32_bf16(a, b, c, 0, 0, 0);
}

// ---- local dtype probe (no cross-kernel dep): bf16 data -> sane exponent
// fields in even u16s; f32 data -> uniform-random. Returns 1 if f32.
__device__ __forceinline__ int probe_f32(const unsigned short* x) {
  int lane = threadIdx.x & 63;
  unsigned short v = x[2 * lane];
  int e = (v >> 7) & 0xFF;
  int sane = (e >= 90 && e <= 160) ? 1 : 0;
  #pragma unroll
  for (int s = 1; s < 64; s <<= 1) sane += __shfl_xor(sane, s, 64);
  return (sane >= 48) ? 0 : 1;
}

// ---- prep: convert x,Wo to bf16 AND transpose Wq/Wk/Wv, one launch -------
// grid = NCONV + 768. Flag computed locally per block (x is L2-broadcast).
__global__ __launch_bounds__(256)
void prep(const void* __restrict__ x, const void* __restrict__ Wq,
          const void* __restrict__ Wk, const void* __restrict__ Wv,
          const void* __restrict__ Wo,
          bf16* __restrict__ xb, bf16* __restrict__ Wob, bf16* __restrict__ WT) {
  const int f32m = probe_f32((const unsigned short*)x);
  const int bid = blockIdx.x;
  if (bid < NCONV) {
    size_t base = ((size_t)bid * 256 + threadIdx.x) * 8;
    const void* src; bf16* dst; size_t off;
    if (base < (size_t)N_XE) { src = x;  dst = xb;  off = base; }
    else                     { src = Wo; dst = Wob; off = base - N_XE; }
    if (f32m) {
      const float* s = (const float*)src + off;
      float4 a = *(const float4*)s;
      float4 b = *(const float4*)(s + 4);
      bf16x8 o;
      o[0] = (bf16)a.x; o[1] = (bf16)a.y; o[2] = (bf16)a.z; o[3] = (bf16)a.w;
      o[4] = (bf16)b.x; o[5] = (bf16)b.y; o[6] = (bf16)b.z; o[7] = (bf16)b.w;
      *(bf16x8*)(dst + off) = o;
    } else {
      *(bf16x8*)(dst + off) = *(const bf16x8*)((const bf16*)src + off);
    }
  } else {
    __shared__ bf16 Ts[64][72];
    const int tb = bid - NCONV;          // 0..767
    const int wz = tb >> 8;              // 0..2 -> Wq/Wk/Wv
    const int tx = tb & 255;
    const void* W = (wz == 0) ? Wq : (wz == 1) ? Wk : Wv;
    bf16* dst = WT + (size_t)wz * DM * DM;
    const int h  = tx >> 4;
    const int d0 = (tx & 15) * 64;
    const int tid = threadIdx.x;
    #pragma unroll
    for (int p = 0; p < 2; ++p) {
      int idx = p * 256 + tid;
      int dr = idx >> 3, c = idx & 7;
      size_t eoff = (size_t)(h * DM + d0 + dr) * HS + c * 8;
      bf16x8 v;
      if (f32m) {
        const float* s = (const float*)W + eoff;
        #pragma unroll
        for (int j = 0; j < 8; ++j) v[j] = (bf16)s[j];
      } else {
        v = *(const bf16x8*)((const bf16*)W + eoff);
      }
      #pragma unroll
      for (int j = 0; j < 8; ++j) Ts[c * 8 + j][dr] = v[j];
    }
    __syncthreads();
    #pragma unroll
    for (int p = 0; p < 2; ++p) {
      int idx = p * 256 + tid;
      int sr = idx >> 3, c = idx & 7;
      bf16x8 v = *(const bf16x8*)(&Ts[sr][c * 8]);
      *(bf16x8*)(dst + (size_t)(h * 64 + sr) * DM + d0 + c * 8) = v;
    }
  }
}

// ------ 128x128 tile bt-GEMM core, BK=64, 2-phase counted-vmcnt dbuf ------
// r7's proven sync discipline (STAGE(t+1) before compute(t), vmcnt(8),
// 2 barriers/step) at HALF the step count: 16 K-steps of 64 amortize the
// ~1600cy/step fixed sync cost that all BK=32 variants shared.
// LDS [128][64] tiles with the attn-verified XOR-chunk swizzle
// (LDS[row][c] = global[row][c ^ (row&7)], both sides) -> conflict-free.
template<typename EpiF>
__device__ __forceinline__ void gemm128_bt(const bf16* __restrict__ A,
                                           const bf16* __restrict__ BT,
                                           int m0, int n0, EpiF epi) {
  __shared__ bf16 As[2][128 * 64];
  __shared__ bf16 Bs[2][128 * 64];
  const int tid  = threadIdx.x;
  const int wave = tid >> 6, lane = tid & 63;
  const int wr = wave >> 1, wc = wave & 1;
  const int fr = lane & 15, fg = lane >> 4;
  const int srow8 = lane >> 3;           // 8 rows per 1KB issue
  const int schk  = (lane & 7) ^ srow8;  // pre-swizzled source chunk
  f32x4 acc[4][4] = {};

  auto STAGE = [&](int buf, int kt) {
    const int k0 = kt * 64;
    #pragma unroll
    for (int i = 0; i < 4; ++i) {
      int r8 = wave * 32 + i * 8;        // wave-uniform base rows
      async16((char*)&As[buf][0] + (wave * 4 + i) * 1024,
              A + (size_t)(m0 + r8 + srow8) * DM + k0 + schk * 8);
      async16((char*)&Bs[buf][0] + (wave * 4 + i) * 1024,
              BT + (size_t)(n0 + r8 + srow8) * DM + k0 + schk * 8);
    }
  };

  STAGE(0, 0);
  #pragma unroll 1
  for (int kt = 0; kt < 16; ++kt) {
    const int buf = kt & 1;
    if (kt + 1 < 16) {
      STAGE(buf ^ 1, kt + 1);
      asm volatile("s_waitcnt vmcnt(8)" ::: "memory");  // tile kt landed
    } else {
      asm volatile("s_waitcnt vmcnt(0)" ::: "memory");
    }
    __builtin_amdgcn_s_barrier();        // tile kt visible to all waves
    bf16x8 af[4][2], bv[4][2];
    #pragma unroll
    for (int mi = 0; mi < 4; ++mi) {
      int r = wr * 64 + mi * 16 + fr;
      #pragma unroll
      for (int kk = 0; kk < 2; ++kk)
        af[mi][kk] = *(const bf16x8*)(&As[buf][r * 64 + (((kk * 4 + fg) ^ (r & 7)) * 8)]);
    }
    #pragma unroll
    for (int ni = 0; ni < 4; ++ni) {
      int r = wc * 64 + ni * 16 + fr;
      #pragma unroll
      for (int kk = 0; kk < 2; ++kk)
        bv[ni][kk] = *(const bf16x8*)(&Bs[buf][r * 64 + (((kk * 4 + fg) ^ (r & 7)) * 8)]);
    }
    __builtin_amdgcn_s_setprio(1);
    #pragma unroll
    for (int mi = 0; mi < 4; ++mi)
      #pragma unroll
      for (int ni = 0; ni < 4; ++ni)
        #pragma unroll
        for (int kk = 0; kk < 2; ++kk)
          acc[mi][ni] = mfma16(af[mi][kk], bv[ni][kk], acc[mi][ni]);
    __builtin_amdgcn_s_setprio(0);
    __builtin_amdgcn_s_barrier();        // reads of buf done before re-stage
  }
  #pragma unroll
  for (int mi = 0; mi < 4; ++mi)
    #pragma unroll
    for (int ni = 0; ni < 4; ++ni)
      #pragma unroll
      for (int r = 0; r < 4; ++r) {
        int m = m0 + wr * 64 + mi * 16 + fg * 4 + r;
        int n = n0 + wc * 64 + ni * 16 + fr;
        epi(m, n, acc[mi][ni][r]);
      }
}

// QKV projection, all z in one launch. grid(1536):
// m_tile = bid & 63 (64 = 0 mod 8 keeps all same-m blocks on ONE XCD for
// A-panel L2 locality — FETCH-verified 41 MB), nz = bid >> 6.
__global__ __launch_bounds__(256, 2)
void qkv_gemm(const bf16* __restrict__ x, const bf16* __restrict__ WT,
              bf16* __restrict__ Qb, bf16* __restrict__ Kb, bf16* __restrict__ Vt) {
  const int bid = blockIdx.x;
  const int m0 = (bid & 63) * 128;
  const int nz = bid >> 6;
  const int z  = nz >> 3;
  const int n0 = (nz & 7) * 128;
  const bf16* BT = WT + (size_t)z * DM * DM;
  gemm128_bt(x, BT, m0, n0, [&](int m, int n, float v) {
    int b = m >> 11, t = m & 2047, h = n >> 6, s = n & 63;
    if (z == 0)
      Qb[((size_t)(b * NH + h) * SEQ + t) * HS + s] = (bf16)v;
    else if (z == 1)
      Kb[((size_t)(b * NH + h) * SEQ + t) * HS + s] = (bf16)v;
    else
      Vt[((size_t)(b * NH + h) * HS + s) * SEQ + t] = (bf16)v;
  });
}

__global__ __launch_bounds__(256, 2)
void out_gemm(const bf16* __restrict__ att, const bf16* __restrict__ Wob,
              const void* __restrict__ bo, void* __restrict__ out,
              const unsigned short* __restrict__ xprobe) {
  const int f32m = probe_f32(xprobe);
  const int bid = blockIdx.x;
  const int m0 = (bid & 63) * 128;
  const int n0 = (bid >> 6) * 128;
  gemm128_bt(att, Wob, m0, n0, [&](int m, int n, float v) {
    float bv = f32m ? ((const float*)bo)[n] : (float)((const bf16*)bo)[n];
    float o = v + bv;
    if (f32m) ((float*)out)[(size_t)m * DM + n] = o;
    else      ((bf16*)out)[(size_t)m * DM + n] = (bf16)o;
  });
}

// -------------------- causal flash attention v4 (unchanged) ---------------
#define KVB  64
__global__ __launch_bounds__(256, 2)
void attn_kernel(const bf16* __restrict__ Qb, const bf16* __restrict__ Kb,
                 const bf16* __restrict__ Vt, bf16* __restrict__ att) {
  __shared__ bf16 Ks[2][64][64];      // [buf][kv][d]  (chunks swizzled)
  __shared__ bf16 Vs[2][64][64];      // [buf][d][kv]  (chunks swizzled)
  __shared__ bf16 Ps[4][2][16][64];   // per-wave P    (chunks swizzled)
  const int wave = threadIdx.x >> 6, lane = threadIdx.x & 63;
  const int fr = lane & 15, fg = lane >> 4;
  const int pair = blockIdx.x;        // 0..7
  const int bh = blockIdx.y;
  const bf16* Qp = Qb + (size_t)bh * SEQ * HS;
  const bf16* Kp = Kb + (size_t)bh * SEQ * HS;
  const bf16* Vp = Vt + (size_t)bh * HS * SEQ;
  const int b = bh >> 4, h = bh & 15;

  const int srow8 = lane >> 3;
  const int schk  = (lane & 7) ^ srow8;

  #pragma unroll
  for (int seg = 0; seg < 2; ++seg) {
    const int qb = seg == 0 ? (15 - pair) : pair;   // heavy member first
    const int q0 = qb * 128 + wave * 32;
    const int kv_hi = q0 + 32;
    const int nt = (qb + 1) * 2;

    bf16x8 qf[2][2];
    #pragma unroll
    for (int qt = 0; qt < 2; ++qt)
      #pragma unroll
      for (int hh = 0; hh < 2; ++hh)
        qf[qt][hh] = *(const bf16x8*)(Qp + (size_t)(q0 + qt * 16 + fr) * HS + hh * 32 + fg * 8);

    float rs[2][4] = {};
    f32x4 accO[2][4] = {};

    auto STAGE = [&](int buf, int kvb) {
      #pragma unroll
      for (int i = 0; i < 2; ++i) {
        int r8 = wave * 16 + i * 8;
        async16(&Ks[buf][r8][0], Kp + (size_t)(kvb + r8 + srow8) * HS + schk * 8);
        async16(&Vs[buf][r8][0], Vp + (size_t)(r8 + srow8) * SEQ + kvb + schk * 8);
      }
    };

    STAGE(0, 0);
    for (int t = 0; t < nt; ++t) {
      const int buf = t & 1;
      const int kvb = t * KVB;
      if (t + 1 < nt) {
        STAGE(buf ^ 1, kvb + KVB);
        asm volatile("s_waitcnt vmcnt(4)" ::: "memory");  // tile t landed
      } else {
        asm volatile("s_waitcnt vmcnt(0)" ::: "memory");
      }
      __builtin_amdgcn_s_barrier();      // all waves' tile-t data visible
      if (kvb < kv_hi) {
        bf16x8 kf[4][2];
        #pragma unroll
        for (int s = 0; s < 4; ++s)
          #pragma unroll
          for (int hh = 0; hh < 2; ++hh)
            kf[s][hh] = *(const bf16x8*)(&Ks[buf][s * 16 + fr][((hh * 4 + fg) ^ (fr & 7)) * 8]);
        // WAR: previous tile's P reads retired before overwriting Ps
        asm volatile("s_waitcnt lgkmcnt(0)" ::: "memory");

        #pragma unroll
        for (int qt = 0; qt < 2; ++qt) {
          f32x4 sc[4];
          #pragma unroll
          for (int s = 0; s < 4; ++s) {
            sc[s] = f32x4{0.f, 0.f, 0.f, 0.f};
            sc[s] = mfma16(qf[qt][0], kf[s][0], sc[s]);
            sc[s] = mfma16(qf[qt][1], kf[s][1], sc[s]);
          }
          #pragma unroll
          for (int s = 0; s < 4; ++s)
            #pragma unroll
            for (int r = 0; r < 4; ++r) {
              int qrow = q0 + qt * 16 + fg * 4 + r;
              int col  = kvb + s * 16 + fr;
              float p = __expf(sc[s][r] * 0.125f);
              p = (col <= qrow) ? p : 0.f;
              rs[qt][r] += p;
              int row = fg * 4 + r;
              int swz = (s * 2 + (fr >> 3)) ^ (row & 7);
              Ps[wave][qt][row][swz * 8 + (fr & 7)] = (bf16)p;
            }
        }
        asm volatile("s_waitcnt lgkmcnt(0)" ::: "memory");  // P visible
        __builtin_amdgcn_sched_barrier(0);
        bf16x8 pf[2][2];
        #pragma unroll
        for (int qt = 0; qt < 2; ++qt)
          #pragma unroll
          for (int kc = 0; kc < 2; ++kc)
            pf[qt][kc] = *(const bf16x8*)(&Ps[wave][qt][fr][(((kc * 4 + fg) ^ (fr & 7))) * 8]);
        #pragma unroll
        for (int st = 0; st < 4; ++st) {
          bf16x8 vf0 = *(const bf16x8*)(&Vs[buf][st * 16 + fr][((fg) ^ (fr & 7)) * 8]);
          bf16x8 vf1 = *(const bf16x8*)(&Vs[buf][st * 16 + fr][((4 + fg) ^ (fr & 7)) * 8]);
          #pragma unroll
          for (int qt = 0; qt < 2; ++qt) {
            accO[qt][st] = mfma16(pf[qt][0], vf0, accO[qt][st]);
            accO[qt][st] = mfma16(pf[qt][1], vf1, accO[qt][st]);
          }
        }
      }
      __builtin_amdgcn_s_barrier();      // all reads of buf done before reuse
    }

    // epilogue: one cross-lane sum reduce (over the 16 fr lanes), then store
    #pragma unroll
    for (int sh = 1; sh < 16; sh <<= 1)
      #pragma unroll
      for (int qt = 0; qt < 2; ++qt)
        #pragma unroll
        for (int r = 0; r < 4; ++r)
          rs[qt][r] += __shfl_xor(rs[qt][r], sh, 64);
    #pragma unroll
    for (int qt = 0; qt < 2; ++qt)
      #pragma unroll
      for (int st = 0; st < 4; ++st)
        #pragma unroll
        for (int r = 0; r < 4; ++r) {
          int qrow = q0 + qt * 16 + fg * 4 + r;
          float o = accO[qt][st][r] / rs[qt][r];
          att[((size_t)(b * SEQ + qrow)) * DM + h * 64 + st * 16 + fr] = (bf16)o;
        }
  }
}

// --------------------------------------------------------------------------
extern "C" void kernel_launch(void* const* d_in, const int* in_sizes, int n_in,
                              void* d_out, int out_size, void* d_ws, size_t ws_size,
                              hipStream_t stream) {
  const void* x  = d_in[0];
  const void* Wq = d_in[1];
  const void* Wk = d_in[2];
  const void* Wv = d_in[3];
  const void* Wo = d_in[4];
  const void* bo = d_in[5];

  char* ws = (char*)d_ws;
  bf16* xb  = (bf16*)(ws);                              // 16 MiB
  bf16* WT  = (bf16*)(ws + ((size_t)16 << 20));         // 6 MiB (QKV^T)
  bf16* Wob = (bf16*)(ws + ((size_t)22 << 20));         // 2 MiB
  bf16* Qb  = (bf16*)(ws + ((size_t)24 << 20));         // 16 MiB
  bf16* Kb  = (bf16*)(ws + ((size_t)40 << 20));         // 16 MiB
  bf16* Vt  = (bf16*)(ws + ((size_t)56 << 20));         // 16 MiB -> 72 MiB
  bf16* att = xb;   // x is consumed after qkv_gemm; reuse its buffer

  prep<<<dim3(NCONV + 768), 256, 0, stream>>>(x, Wq, Wk, Wv, Wo, xb, Wob, WT);
  qkv_gemm<<<dim3(1536), 256, 0, stream>>>(xb, WT, Qb, Kb, Vt);
  attn_kernel<<<dim3(8, BATCH * NH), 256, 0, stream>>>(Qb, Kb, Vt, att);
  out_gemm<<<dim3(512), 256, 0, stream>>>(att, Wob, bo, d_out,
                                          (const unsigned short*)x);
}